// Round 1
// baseline (221.780 us; speedup 1.0000x reference)
//
#include <hip/hip_runtime.h>
#include <math.h>

// RoPE-2D, fused rotation:
//   R(col_ang) * R(row_ang) = R(row_ang + col_ang)   (2D rotations compose additively)
// x layout: [B=32, S=1024, H=16, D=64] fp32, pairs are (d=2k, d=2k+1).
// One thread = one float4 = pairs k and k+1 of some (b,s,h).
// All dims are powers of two except cols (runtime), so decode is shifts + one div.

#define S_LOG2 10   // S = 1024
#define H_LOG2 4    // H = 16
#define D_LOG2 6    // D = 64

__global__ __launch_bounds__(256) void rope2d_kernel(
    const float4* __restrict__ x,
    const int* __restrict__ grid_sizes,
    float4* __restrict__ out,
    int n4)
{
    int g = blockIdx.x * 256 + threadIdx.x;
    if (g >= n4) return;

    int e    = g << 2;                 // flat element index of v.x
    int k    = (e & ((1 << D_LOG2) - 1)) >> 1;   // pair index (0..31), covers k and k+1
    int bs   = e >> (D_LOG2 + H_LOG2);           // b*S + s   (head index irrelevant)
    int s    = bs & ((1 << S_LOG2) - 1);
    int b    = bs >> S_LOG2;

    int cols = grid_sizes[2 * b + 1];
    int i    = s / cols;               // row index
    int j    = s - i * cols;           // col index
    float ij = (float)(i + j);         // combined rotation multiplier

    // theta_k = 10000^(-k/32) = exp2(k * -log2(10000)/32)
    const float C       = -0.41524101186092029f;  // -log2(10000)/32
    const float INV_2PI = 0.15915494309189535f;

    float t0 = __builtin_amdgcn_exp2f((float)k * C);
    float t1 = __builtin_amdgcn_exp2f((float)(k + 1) * C);

    // angle in revolutions, reduced to [0,1) for v_sin/v_cos
    float r0 = ij * t0 * INV_2PI;  r0 -= floorf(r0);
    float r1 = ij * t1 * INV_2PI;  r1 -= floorf(r1);

    float s0 = __builtin_amdgcn_sinf(r0);
    float c0 = __builtin_amdgcn_cosf(r0);
    float s1 = __builtin_amdgcn_sinf(r1);
    float c1 = __builtin_amdgcn_cosf(r1);

    float4 v = x[g];
    float4 o;
    o.x = v.x * c0 - v.y * s0;
    o.y = v.y * c0 + v.x * s0;
    o.z = v.z * c1 - v.w * s1;
    o.w = v.w * c1 + v.z * s1;
    out[g] = o;
}

extern "C" void kernel_launch(void* const* d_in, const int* in_sizes, int n_in,
                              void* d_out, int out_size, void* d_ws, size_t ws_size,
                              hipStream_t stream) {
    const float4* x  = (const float4*)d_in[0];
    const int*    gs = (const int*)d_in[1];
    float4*       o  = (float4*)d_out;

    int n4 = in_sizes[0] >> 2;          // 33,554,432 / 4 = 8,388,608 float4s
    int blocks = (n4 + 255) / 256;      // 32768 blocks, exact coverage

    rope2d_kernel<<<blocks, 256, 0, stream>>>(x, gs, o, n4);
}

// Round 3
// 218.022 us; speedup vs baseline: 1.0172x; 1.0172x over previous
//
#include <hip/hip_runtime.h>
#include <math.h>

// RoPE-2D fused: R(col)*R(row) = R(row+col) (2D rotations compose additively).
// x: [B=32, S=1024, H=16, D=64] fp32. One (b,s) slice = H*D = 1024 floats = 256 float4s.
// Block = 256 threads, handles 4 consecutive (b,s) slices (4096 floats, 64 B/thread).
// Within a chunk, (b,s) is wave-uniform -> cols load, u32 div, i+j are scalar-once.
// k (theta index) depends only on tid -> exp2 computed once, reused for all 4 chunks.
// 4 independent loads issued up front for latency hiding; nontemporal (streaming).
// NOTE: nontemporal builtins need a native vector type, not HIP's float4 class.

typedef float vfloat4 __attribute__((ext_vector_type(4)));

#define CHUNKS 4

__global__ __launch_bounds__(256) void rope2d_kernel(
    const vfloat4* __restrict__ x,
    const int* __restrict__ grid_sizes,
    vfloat4* __restrict__ out)
{
    const int tid   = threadIdx.x;
    const int base4 = blockIdx.x * (256 * CHUNKS);   // first float4 index of this block
    const int bs0   = blockIdx.x * CHUNKS;           // first (b*S+s) slice index

    // pair index within D: e_in_slice = tid*4 -> k = ((tid*4) & 63) >> 1 = (tid & 15)*2
    const int k = (tid & 15) << 1;

    const float C       = -0.41524101186092029f;  // -log2(10000)/32
    const float INV_2PI = 0.15915494309189535f;

    const float t0 = __builtin_amdgcn_exp2f((float)k * C);
    const float t1 = __builtin_amdgcn_exp2f((float)(k + 1) * C);

    // Issue all 4 loads before any compute (4 outstanding vmem ops per wave).
    vfloat4 v[CHUNKS];
#pragma unroll
    for (int c = 0; c < CHUNKS; ++c)
        v[c] = __builtin_nontemporal_load(&x[base4 + c * 256 + tid]);

#pragma unroll
    for (int c = 0; c < CHUNKS; ++c) {
        const int bs   = bs0 + c;                 // wave-uniform
        const int s    = bs & 1023;               // S = 1024
        const int b    = bs >> 10;
        const int cols = grid_sizes[2 * b + 1];   // uniform scalar load
        const int i    = s / cols;                // uniform division, once per 1024 elems
        const int j    = s - i * cols;
        const float ij = (float)(i + j);

        float r0 = ij * t0 * INV_2PI;  r0 -= floorf(r0);
        float r1 = ij * t1 * INV_2PI;  r1 -= floorf(r1);

        const float s0 = __builtin_amdgcn_sinf(r0);
        const float c0 = __builtin_amdgcn_cosf(r0);
        const float s1 = __builtin_amdgcn_sinf(r1);
        const float c1 = __builtin_amdgcn_cosf(r1);

        vfloat4 o;
        o.x = v[c].x * c0 - v[c].y * s0;
        o.y = v[c].y * c0 + v[c].x * s0;
        o.z = v[c].z * c1 - v[c].w * s1;
        o.w = v[c].w * c1 + v[c].z * s1;
        __builtin_nontemporal_store(o, &out[base4 + c * 256 + tid]);
    }
}

extern "C" void kernel_launch(void* const* d_in, const int* in_sizes, int n_in,
                              void* d_out, int out_size, void* d_ws, size_t ws_size,
                              hipStream_t stream) {
    const vfloat4* x  = (const vfloat4*)d_in[0];
    const int*     gs = (const int*)d_in[1];
    vfloat4*       o  = (vfloat4*)d_out;

    const int n4     = in_sizes[0] >> 2;            // 8,388,608 float4s
    const int blocks = n4 / (256 * CHUNKS);         // 8192 blocks, exact coverage

    rope2d_kernel<<<blocks, 256, 0, stream>>>(x, gs, o);
}